// Round 1
// baseline (1100.234 us; speedup 1.0000x reference)
//
#include <hip/hip_runtime.h>

// Sparse 3D submanifold conv, fp32 VALU baseline.
// out = feats @ K[13]  (dense, all N rows)
// out[omap[k,m]] += feats[imap[k,m]] @ K[koff[k]]  for 26 offset slices (atomics)

#define N_PTS  100000
#define MPAD   60000
#define C_IN   64
#define C_OUT  64
#define NOFF   26

constexpr int ROWS_PER_PASS  = 16;               // 4 waves * 4 rows
constexpr int PASSES         = 15;
constexpr int ROWS_PER_BLOCK = ROWS_PER_PASS * PASSES;   // 240
constexpr int XROW_STRIDE    = 68;               // floats; 272B, 16B-aligned, bank-disjoint across rows

template<bool IS_CENTER>
__global__ __launch_bounds__(256, 4)
void spconv_kernel(const float* __restrict__ feats,
                   const float* __restrict__ kern,   // (27,64,64)
                   const int*   __restrict__ imap,   // (26,MPAD) or null
                   const int*   __restrict__ omap,
                   float*       __restrict__ out,
                   int nrows)
{
    __shared__ float WL[C_IN * C_OUT];          // 16 KB weight slice
    __shared__ float XS[4][4 * XROW_STRIDE];    // per-wave row buffers, ~4.25 KB

    const int tid  = threadIdx.x;
    const int wave = tid >> 6;
    const int lane = tid & 63;
    const int r    = lane >> 4;    // row subgroup within wave (0..3)
    const int t    = lane & 15;    // output quad (outputs 4t..4t+3)

    const int kk = IS_CENTER ? 13 : (blockIdx.y + (blockIdx.y >= 13 ? 1 : 0));
    const float* Wk = kern + kk * (C_IN * C_OUT);

    // stage weight slice: 4096 floats = 1024 float4 by 256 threads
    {
        const float4* src = (const float4*)Wk;
        float4*       dst = (float4*)WL;
        #pragma unroll
        for (int idx = 0; idx < 4; ++idx)
            dst[tid + idx * 256] = src[tid + idx * 256];
    }
    __syncthreads();

    const int* im = IS_CENTER ? nullptr : imap + (size_t)blockIdx.y * MPAD;
    const int* om = IS_CENTER ? nullptr : omap + (size_t)blockIdx.y * MPAD;

    float* xrow = &XS[wave][r * XROW_STRIDE];
    const int base = blockIdx.x * ROWS_PER_BLOCK;

    for (int p = 0; p < PASSES; ++p) {
        const int m = base + p * ROWS_PER_PASS + wave * 4 + r;
        int i, dsti;
        bool valid;
        if (IS_CENTER) {
            valid = (m < nrows);
            i = m; dsti = m;
        } else {
            const bool inb = (m < nrows);
            i    = inb ? im[m] : -1;
            dsti = inb ? om[m] : 0;
            valid = (i >= 0);
        }
        if (!__any(valid ? 1 : 0)) continue;   // whole-wave skip (padded tail)

        const int isafe = valid ? i : 0;
        // gather input row: 16 lanes * float4 = 64 floats, coalesced
        const float4 xv = ((const float4*)(feats + (size_t)isafe * C_IN))[t];
        ((float4*)xrow)[t] = xv;
        // wave-private LDS RAW; compiler inserts lgkmcnt wait

        float4 y; y.x = 0.f; y.y = 0.f; y.z = 0.f; y.w = 0.f;
        #pragma unroll
        for (int c4 = 0; c4 < 16; ++c4) {
            const float4 xq = ((const float4*)xrow)[c4];
            const float* wb = WL + (c4 * 4) * C_OUT + t * 4;
            const float4 w0 = *(const float4*)(wb);
            const float4 w1 = *(const float4*)(wb + C_OUT);
            const float4 w2 = *(const float4*)(wb + 2 * C_OUT);
            const float4 w3 = *(const float4*)(wb + 3 * C_OUT);
            y.x += xq.x * w0.x + xq.y * w1.x + xq.z * w2.x + xq.w * w3.x;
            y.y += xq.x * w0.y + xq.y * w1.y + xq.z * w2.y + xq.w * w3.y;
            y.z += xq.x * w0.z + xq.y * w1.z + xq.z * w2.z + xq.w * w3.z;
            y.w += xq.x * w0.w + xq.y * w1.w + xq.z * w2.w + xq.w * w3.w;
        }

        if (valid) {
            float* op = out + (size_t)dsti * C_OUT + t * 4;
            if (IS_CENTER) {
                *(float4*)op = y;
            } else {
                atomicAdd(op + 0, y.x);
                atomicAdd(op + 1, y.y);
                atomicAdd(op + 2, y.z);
                atomicAdd(op + 3, y.w);
            }
        }
    }
}

extern "C" void kernel_launch(void* const* d_in, const int* in_sizes, int n_in,
                              void* d_out, int out_size, void* d_ws, size_t ws_size,
                              hipStream_t stream) {
    const float* feats = (const float*)d_in[0];
    const float* kern  = (const float*)d_in[1];
    const int*   imap  = (const int*)d_in[2];
    const int*   omap  = (const int*)d_in[3];
    float*       out   = (float*)d_out;

    dim3 blk(256);
    // center: initializes every output row (harness poisons d_out)
    dim3 gA((N_PTS + ROWS_PER_BLOCK - 1) / ROWS_PER_BLOCK, 1);
    spconv_kernel<true><<<gA, blk, 0, stream>>>(feats, kern, nullptr, nullptr, out, N_PTS);
    // 26 offset slices, atomic scatter-add
    dim3 gB(MPAD / ROWS_PER_BLOCK, NOFF);
    spconv_kernel<false><<<gB, blk, 0, stream>>>(feats, kern, imap, omap, out, MPAD);
}

// Round 3
// 167.442 us; speedup vs baseline: 6.5708x; 6.5708x over previous
//
#include <hip/hip_runtime.h>

// Sparse 3D submanifold conv — gather formulation + bf16 MFMA.
//   Phase 0: memset nbr table to -1
//   Phase 1: feats fp32 -> bf16 table (plus one zero row); weights -> B-fragment
//            swizzled bf16 table; nbr[s][omap[s,m]] = imap[s,m] (conflict-free scatter;
//            dsts are unique within a slice).
//   Phase 2: each wave owns 32 output rows; loops 27 taps; A-frags gathered
//            directly from bf16 feats (global_load_dwordx4), B-frags from the
//            pre-swizzled table; 16x16x32 bf16 MFMA; registers accumulate;
//            ONE store per output element. Zero atomics, zero LDS.

#define N_PTS 100000
#define MPAD  60000
#define C     64
#define NSL   27          // slices 0..25 = offset taps, 26 = center (kernel[13])

typedef short bf16x8 __attribute__((ext_vector_type(8)));   // 8 x bf16 bits (4 VGPRs)
typedef float f32x4  __attribute__((ext_vector_type(4)));

// fp32 -> bf16 (round-to-nearest-even), bit-level
static __device__ inline unsigned short f2bf(float x) {
    unsigned int u = __float_as_uint(x);
    u += 0x7fffu + ((u >> 16) & 1u);
    return (unsigned short)(u >> 16);
}

// workspace layout (bytes)
#define FEATS16_BYTES ((size_t)(N_PTS + 1) * C * 2)             // 12,800,128 (+1 zero row)
#define WFRAG_OFF     (((FEATS16_BYTES) + 255) & ~(size_t)255)  // 12,800,256
#define WFRAG_BYTES   ((size_t)NSL * 2 * 4 * 64 * 16)           // 221,184
#define NBR_OFF       (WFRAG_OFF + WFRAG_BYTES)                 // 13,021,440
#define NBR_BYTES     ((size_t)26 * N_PTS * 4)                  // 10,400,000

// ---- phase 1a: feats fp32 -> bf16 (8 elems/thread) + zero row ----
__global__ __launch_bounds__(256) void prep_feats(const float* __restrict__ feats,
                                                  unsigned short* __restrict__ f16) {
    const int idx = blockIdx.x * 256 + threadIdx.x;
    const int total = (N_PTS * C) / 8;   // 800000 vectors of 8
    bf16x8* dst = (bf16x8*)f16;
    if (idx < total) {
        const float4* src = (const float4*)feats;
        const float4 a = src[2 * idx];
        const float4 b = src[2 * idx + 1];
        bf16x8 v;
        v[0] = (short)f2bf(a.x); v[1] = (short)f2bf(a.y);
        v[2] = (short)f2bf(a.z); v[3] = (short)f2bf(a.w);
        v[4] = (short)f2bf(b.x); v[5] = (short)f2bf(b.y);
        v[6] = (short)f2bf(b.z); v[7] = (short)f2bf(b.w);
        dst[idx] = v;
    } else if (idx < total + 8) {        // zero row (row N_PTS): 128 B = 8 vectors
        bf16x8 z = (bf16x8){0, 0, 0, 0, 0, 0, 0, 0};
        dst[idx] = z;
    }
}

// ---- phase 1b: weights -> B-fragment swizzled bf16 table ----
// B-frag for 16x16x32 bf16: lane (q=lane>>4, t=lane&15) holds B[k = 32*kk + 8q + j][n = 16*ct + t]
// table index: ((s*2 + kk)*4 + ct)*64 + lane, 16 B each
__global__ __launch_bounds__(256) void prep_wfrag(const float* __restrict__ kern,
                                                  unsigned short* __restrict__ wf) {
    const int idx = blockIdx.x * 256 + threadIdx.x;
    if (idx >= NSL * 2 * 4 * 64) return;
    const int lane = idx & 63;
    const int rest = idx >> 6;
    const int ct = rest & 3;
    const int kk = (rest >> 2) & 1;
    const int s  = rest >> 3;
    const int q = lane >> 4, t = lane & 15;
    const int ksrc = (s == 26) ? 13 : (s + (s >= 13 ? 1 : 0));
    const int k0 = kk * 32 + q * 8;
    const int n  = ct * 16 + t;
    const float* w = kern + (size_t)ksrc * 4096 + n;
    bf16x8 v;
    #pragma unroll
    for (int j = 0; j < 8; ++j) v[j] = (short)f2bf(w[(size_t)(k0 + j) * 64]);
    ((bf16x8*)wf)[idx] = v;
}

// ---- phase 1c: dst-indexed neighbor table (conflict-free scatter) ----
__global__ __launch_bounds__(256) void prep_nbr(const int* __restrict__ imap,
                                                const int* __restrict__ omap,
                                                int* __restrict__ nbr) {
    const int m = blockIdx.x * 256 + threadIdx.x;
    const int s = blockIdx.y;
    if (m < MPAD) {
        const int i = imap[(size_t)s * MPAD + m];
        if (i >= 0) nbr[(size_t)s * N_PTS + omap[(size_t)s * MPAD + m]] = i;
    }
}

// ---- phase 2: main MFMA gather kernel ----
// block = 256 thr (4 waves); wave owns 32 rows (2 tiles of 16); block = 128 rows
__global__ __launch_bounds__(256) void spconv_main(const unsigned short* __restrict__ f16,
                                                   const unsigned short* __restrict__ wf,
                                                   const int* __restrict__ nbr,
                                                   float* __restrict__ out) {
    const int lane = threadIdx.x & 63;
    const int wave = threadIdx.x >> 6;
    const int q = lane >> 4, t = lane & 15;
    const int R0 = blockIdx.x * 128 + wave * 32;

    f32x4 acc[2][4];
    #pragma unroll
    for (int a = 0; a < 2; ++a)
        #pragma unroll
        for (int c = 0; c < 4; ++c)
            acc[a][c] = (f32x4){0.f, 0.f, 0.f, 0.f};

    const bf16x8* wfv = (const bf16x8*)wf;

    for (int s = 0; s < NSL; ++s) {
        // B fragments for this tap: 8 x 16B per lane, L1/L2-hot
        bf16x8 B[2][4];
        #pragma unroll
        for (int kk = 0; kk < 2; ++kk)
            #pragma unroll
            for (int ct = 0; ct < 4; ++ct)
                B[kk][ct] = wfv[s * 512 + kk * 256 + ct * 64 + lane];

        #pragma unroll
        for (int tile = 0; tile < 2; ++tile) {
            const int row = R0 + tile * 16 + t;
            int j = -1;
            if (row < N_PTS)
                j = (s == 26) ? row : nbr[(size_t)s * N_PTS + row];
            if (!__any(j >= 0)) continue;           // whole tile empty for this tap
            const int jz = (j >= 0) ? j : N_PTS;    // invalid -> zero row
            // A-frag: lane (q,t) holds X[row(t)][k = 32*kk + 8q + j] -> 16B contiguous
            const bf16x8* ar = (const bf16x8*)(f16 + (size_t)jz * C);
            const bf16x8 A0 = ar[q];
            const bf16x8 A1 = ar[4 + q];
            #pragma unroll
            for (int ct = 0; ct < 4; ++ct)
                acc[tile][ct] = __builtin_amdgcn_mfma_f32_16x16x32_bf16(A0, B[0][ct], acc[tile][ct], 0, 0, 0);
            #pragma unroll
            for (int ct = 0; ct < 4; ++ct)
                acc[tile][ct] = __builtin_amdgcn_mfma_f32_16x16x32_bf16(A1, B[1][ct], acc[tile][ct], 0, 0, 0);
        }
    }

    // epilogue: D layout col = lane&15, row = 4q + reg
    #pragma unroll
    for (int tile = 0; tile < 2; ++tile) {
        #pragma unroll
        for (int i = 0; i < 4; ++i) {
            const int row = R0 + tile * 16 + 4 * q + i;
            if (row < N_PTS) {
                #pragma unroll
                for (int ct = 0; ct < 4; ++ct)
                    out[(size_t)row * C + ct * 16 + t] = acc[tile][ct][i];
            }
        }
    }
}

extern "C" void kernel_launch(void* const* d_in, const int* in_sizes, int n_in,
                              void* d_out, int out_size, void* d_ws, size_t ws_size,
                              hipStream_t stream) {
    const float* feats = (const float*)d_in[0];
    const float* kern  = (const float*)d_in[1];
    const int*   imap  = (const int*)d_in[2];
    const int*   omap  = (const int*)d_in[3];

    char* ws = (char*)d_ws;
    unsigned short* f16 = (unsigned short*)ws;
    unsigned short* wf  = (unsigned short*)(ws + WFRAG_OFF);
    int*            nbr = (int*)(ws + NBR_OFF);

    hipMemsetAsync(nbr, 0xFF, NBR_BYTES, stream);   // nbr = -1

    prep_feats<<<dim3((800008 + 255) / 256), dim3(256), 0, stream>>>(feats, f16);
    prep_wfrag<<<dim3((NSL * 2 * 4 * 64 + 255) / 256), dim3(256), 0, stream>>>(kern, wf);
    prep_nbr<<<dim3((MPAD + 255) / 256, 26), dim3(256), 0, stream>>>(imap, omap, nbr);

    spconv_main<<<dim3((N_PTS + 127) / 128), dim3(256), 0, stream>>>(
        f16, wf, nbr, (float*)d_out);
}

// Round 4
// 166.884 us; speedup vs baseline: 6.5928x; 1.0033x over previous
//
#include <hip/hip_runtime.h>

// Sparse 3D submanifold conv — gather formulation + bf16 MFMA, pipelined.
//   Launch 1 (prep_all): feats fp32->bf16 (+zero row), weights -> B-frag
//                        swizzled table, nbr table = -1 (replaces memset).
//   Launch 2 (prep_nbr): nbr[s][omap[s,m]] = imap[s,m] (dsts unique per slice).
//   Launch 3 (spconv_main): wave owns 32 rows; 27 taps (center folded as tap 26),
//                           branch-free, j prefetched at distance 2, A-frags at
//                           distance 1, fully unrolled; one store per element.

#define N_PTS 100000
#define MPAD  60000
#define C     64
#define NSL   27          // taps 0..25 = offsets, 26 = center (kernel[13])

typedef short bf16x8 __attribute__((ext_vector_type(8)));   // 8 x bf16 bits (4 VGPRs)
typedef float f32x4  __attribute__((ext_vector_type(4)));

static __device__ inline unsigned short f2bf(float x) {
    unsigned int u = __float_as_uint(x);
    u += 0x7fffu + ((u >> 16) & 1u);
    return (unsigned short)(u >> 16);
}

// workspace layout (bytes)
#define FEATS16_BYTES ((size_t)(N_PTS + 1) * C * 2)             // 12,800,128 (+1 zero row)
#define WFRAG_OFF     (((FEATS16_BYTES) + 255) & ~(size_t)255)  // 12,800,256
#define WFRAG_BYTES   ((size_t)NSL * 2 * 4 * 64 * 16)           // 221,184
#define NBR_OFF       (WFRAG_OFF + WFRAG_BYTES)                 // 13,021,440
#define NBR_BYTES     ((size_t)26 * N_PTS * 4)                  // 10,400,000

// flat work ranges for prep_all
#define FEAT_ITEMS 800008                       // 800000 bf16x8 + 8 zero-row vectors
#define WF_ITEMS   (NSL * 2 * 4 * 64)           // 13824
#define NBRF_ITEMS (26 * N_PTS / 4)             // 650000 int4 fills
#define PREP_TOTAL (FEAT_ITEMS + WF_ITEMS + NBRF_ITEMS)

__global__ __launch_bounds__(256) void prep_all(const float* __restrict__ feats,
                                                const float* __restrict__ kern,
                                                unsigned short* __restrict__ f16,
                                                unsigned short* __restrict__ wf,
                                                int* __restrict__ nbr) {
    const int idx = blockIdx.x * 256 + threadIdx.x;
    if (idx < FEAT_ITEMS) {
        // feats fp32 -> bf16, 8 elems/thread; last 8 items write the zero row
        bf16x8* dst = (bf16x8*)f16;
        if (idx < FEAT_ITEMS - 8) {
            const float4* src = (const float4*)feats;
            const float4 a = src[2 * idx];
            const float4 b = src[2 * idx + 1];
            bf16x8 v;
            v[0] = (short)f2bf(a.x); v[1] = (short)f2bf(a.y);
            v[2] = (short)f2bf(a.z); v[3] = (short)f2bf(a.w);
            v[4] = (short)f2bf(b.x); v[5] = (short)f2bf(b.y);
            v[6] = (short)f2bf(b.z); v[7] = (short)f2bf(b.w);
            dst[idx] = v;
        } else {
            dst[idx] = (bf16x8){0, 0, 0, 0, 0, 0, 0, 0};
        }
    } else if (idx < FEAT_ITEMS + WF_ITEMS) {
        // weights -> B-frag table: lane (q,t) holds B[k=32kk+8q+j][n=16ct+t]
        const int w = idx - FEAT_ITEMS;
        const int lane = w & 63;
        const int rest = w >> 6;
        const int ct = rest & 3;
        const int kk = (rest >> 2) & 1;
        const int s  = rest >> 3;
        const int q = lane >> 4, t = lane & 15;
        const int ksrc = (s == 26) ? 13 : (s + (s >= 13 ? 1 : 0));
        const int k0 = kk * 32 + q * 8;
        const int n  = ct * 16 + t;
        const float* wp = kern + (size_t)ksrc * 4096 + n;
        bf16x8 v;
        #pragma unroll
        for (int j = 0; j < 8; ++j) v[j] = (short)f2bf(wp[(size_t)(k0 + j) * 64]);
        ((bf16x8*)wf)[w] = v;
    } else {
        const int k = idx - (FEAT_ITEMS + WF_ITEMS);
        if (k < NBRF_ITEMS) ((int4*)nbr)[k] = make_int4(-1, -1, -1, -1);
    }
}

// nbr[s][omap[s,m]] = imap[s,m]; int4-vectorized map reads, 4 m per thread
__global__ __launch_bounds__(256) void prep_nbr(const int* __restrict__ imap,
                                                const int* __restrict__ omap,
                                                int* __restrict__ nbr) {
    const int v = blockIdx.x * 256 + threadIdx.x;     // vector index (4 m's)
    const int s = blockIdx.y;
    if (v >= MPAD / 4) return;
    const int4 iv = ((const int4*)(imap + (size_t)s * MPAD))[v];
    const int4 ov = ((const int4*)(omap + (size_t)s * MPAD))[v];
    int* nb = nbr + (size_t)s * N_PTS;
    if (iv.x >= 0) nb[ov.x] = iv.x;
    if (iv.y >= 0) nb[ov.y] = iv.y;
    if (iv.z >= 0) nb[ov.z] = iv.z;
    if (iv.w >= 0) nb[ov.w] = iv.w;
}

// ---- main MFMA gather kernel: 4 waves/block, 32 rows/wave, pipelined ----
__global__ __launch_bounds__(256) void spconv_main(const unsigned short* __restrict__ f16,
                                                   const unsigned short* __restrict__ wf,
                                                   const int* __restrict__ nbr,
                                                   float* __restrict__ out) {
    const int lane = threadIdx.x & 63;
    const int wave = threadIdx.x >> 6;
    const int q = lane >> 4, t = lane & 15;
    const int R0 = blockIdx.x * 128 + wave * 32;
    const int row0 = R0 + t;          // tile 0 row for this lane
    const int row1 = R0 + 16 + t;     // tile 1 row

    const bf16x8* wfv = (const bf16x8*)wf;
    const bf16x8* fv  = (const bf16x8*)f16;

    // raw neighbor index for tap s (center = identity); -1 if out of range
    auto ldj = [&](int s, int row) -> int {
        if (s == 26) return (row < N_PTS) ? row : -1;
        const int rc = (row < N_PTS) ? row : 0;
        const int j = nbr[(size_t)s * N_PTS + rc];
        return (row < N_PTS) ? j : -1;
    };
    auto clampj = [&](int j) -> int {               // invalid -> zero row
        return ((unsigned)j < (unsigned)N_PTS) ? j : N_PTS;
    };

    f32x4 acc[2][4];
    #pragma unroll
    for (int a = 0; a < 2; ++a)
        #pragma unroll
        for (int c = 0; c < 4; ++c)
            acc[a][c] = (f32x4){0.f, 0.f, 0.f, 0.f};

    int j0[NSL], j1[NSL];
    bf16x8 A[NSL][4];                 // [tap][tile0_lo, tile0_hi, tile1_lo, tile1_hi]

    // prologue: j for taps 0,1; A for tap 0
    j0[0] = ldj(0, row0); j1[0] = ldj(0, row1);
    j0[1] = ldj(1, row0); j1[1] = ldj(1, row1);
    {
        const bf16x8* a0 = fv + (size_t)clampj(j0[0]) * 8;
        const bf16x8* a1 = fv + (size_t)clampj(j1[0]) * 8;
        A[0][0] = a0[q]; A[0][1] = a0[4 + q];
        A[0][2] = a1[q]; A[0][3] = a1[4 + q];
    }

    #pragma unroll
    for (int s = 0; s < NSL; ++s) {
        if (s + 2 < NSL) {            // j prefetch, distance 2
            j0[s + 2] = ldj(s + 2, row0);
            j1[s + 2] = ldj(s + 2, row1);
        }
        if (s + 1 < NSL) {            // A prefetch, distance 1
            const bf16x8* a0 = fv + (size_t)clampj(j0[s + 1]) * 8;
            const bf16x8* a1 = fv + (size_t)clampj(j1[s + 1]) * 8;
            A[s + 1][0] = a0[q]; A[s + 1][1] = a0[4 + q];
            A[s + 1][2] = a1[q]; A[s + 1][3] = a1[4 + q];
        }
        // B frags (static addresses — compiler hoists freely)
        bf16x8 B0[4], B1[4];
        #pragma unroll
        for (int ct = 0; ct < 4; ++ct) {
            B0[ct] = wfv[s * 512 + ct * 64 + lane];
            B1[ct] = wfv[s * 512 + 256 + ct * 64 + lane];
        }
        #pragma unroll
        for (int ct = 0; ct < 4; ++ct) {
            acc[0][ct] = __builtin_amdgcn_mfma_f32_16x16x32_bf16(A[s][0], B0[ct], acc[0][ct], 0, 0, 0);
            acc[1][ct] = __builtin_amdgcn_mfma_f32_16x16x32_bf16(A[s][2], B0[ct], acc[1][ct], 0, 0, 0);
        }
        #pragma unroll
        for (int ct = 0; ct < 4; ++ct) {
            acc[0][ct] = __builtin_amdgcn_mfma_f32_16x16x32_bf16(A[s][1], B1[ct], acc[0][ct], 0, 0, 0);
            acc[1][ct] = __builtin_amdgcn_mfma_f32_16x16x32_bf16(A[s][3], B1[ct], acc[1][ct], 0, 0, 0);
        }
    }

    // epilogue: D layout col = lane&15, row = 4q + reg
    #pragma unroll
    for (int tile = 0; tile < 2; ++tile) {
        #pragma unroll
        for (int i = 0; i < 4; ++i) {
            const int row = R0 + tile * 16 + 4 * q + i;
            if (row < N_PTS) {
                #pragma unroll
                for (int ct = 0; ct < 4; ++ct)
                    out[(size_t)row * C + ct * 16 + t] = acc[tile][ct][i];
            }
        }
    }
}

extern "C" void kernel_launch(void* const* d_in, const int* in_sizes, int n_in,
                              void* d_out, int out_size, void* d_ws, size_t ws_size,
                              hipStream_t stream) {
    const float* feats = (const float*)d_in[0];
    const float* kern  = (const float*)d_in[1];
    const int*   imap  = (const int*)d_in[2];
    const int*   omap  = (const int*)d_in[3];

    char* ws = (char*)d_ws;
    unsigned short* f16 = (unsigned short*)ws;
    unsigned short* wf  = (unsigned short*)(ws + WFRAG_OFF);
    int*            nbr = (int*)(ws + NBR_OFF);

    prep_all<<<dim3((PREP_TOTAL + 255) / 256), dim3(256), 0, stream>>>(
        feats, kern, f16, wf, nbr);
    prep_nbr<<<dim3((MPAD / 4 + 255) / 256, 26), dim3(256), 0, stream>>>(
        imap, omap, nbr);
    spconv_main<<<dim3((N_PTS + 127) / 128), dim3(256), 0, stream>>>(
        f16, wf, nbr, (float*)d_out);
}